// Round 3
// baseline (88.617 us; speedup 1.0000x reference)
//
#include <hip/hip_runtime.h>
#include <stdint.h>

// ---------------------------------------------------------------------------
// quantized_conv: bit-serial IMC conv simulation, exact integer path via i8 MFMA
//
// out[b,o,p] = (norm/255) * sum_{c,s,t} 4^(s+t) *
//    ( min(31, sum_f a_s[f]*wp_t[f]) - min(31, sum_f a_s[f]*wn_t[f]) )
// a_s = 2-bit digit s of the 8-bit two's-complement quantized input patch;
// wp_t/wn_t = 2-bit digit t of round(|w|+-/max|w|*255). Digits in 0..3 ->
// per-chunk K=116 dots exact in i32 -> bit-exact vs fp32 ref (R1/R2: absmax=0).
//
// R3: single fused kernel, no workspace. Each block (32m x 32o) computes the
// weight max redundantly (weights L2-resident), quantizes its weight tile and
// unfolds its patches directly into LDS, then MFMA. Operands swapped vs R2
// (weights = A-operand) so stores are p-contiguous (64B segments, not 4B scatter).
// dur_us is dominated by the harness reset floor (~70us of poison fills).
// ---------------------------------------------------------------------------

typedef int v4i __attribute__((ext_vector_type(4)));
typedef unsigned int v4u __attribute__((ext_vector_type(4)));

#define BROW 656   // LDS row stride: 164 dwords == 4 mod 32 banks -> <=2-way (free), 16B aligned

// extract 2-bit field s of each byte in a packed dword vector
__device__ __forceinline__ v4i bits2(v4u w, int s) {
  v4u r = (w >> (unsigned)(2 * s)) & 0x03030303u;
  return (v4i)r;
}

__global__ __launch_bounds__(256) void k_fused(
    const float* __restrict__ in, const float* __restrict__ w,
    float* __restrict__ out)
{
  __shared__ unsigned char Al[32 * BROW];   // patches [m_l][kpos]       20992 B
  __shared__ unsigned char Bl[64 * BROW];   // weights [sign*32+o_l][kpos] 41984 B
  __shared__ float s_part[4];

  int tid = threadIdx.x;
  int bid = blockIdx.x;
  if (bid == 0 && tid == 0) out[262144] = 0.0f;   // second tuple output

  int mtile = bid >> 1;        // 128 tiles of 32 consecutive patch rows
  int ohalf = bid & 1;         // o base = ohalf*32

  // ---- phase 1: zero B chunk-pad dwords (kpos 112..127 per chunk row) ----
  #pragma unroll
  for (int i = 0; i < 5; ++i) {
    int idx = i * 256 + tid;              // [0,1280)
    int loc = idx >> 2, dw = idx & 3;     // 320 (sign,o_l,c) locations
    int sign = loc >= 160 ? 1 : 0;
    int r = loc - sign * 160;
    unsigned int o_l = ((unsigned)r * 52429u) >> 18;   // r/5
    int c = r - (int)o_l * 5;
    ((unsigned int*)Bl)[(sign * 32 + (int)o_l) * 164 + c * 32 + 28 + dw] = 0u;
  }

  // ---- phase 2: unfold + quantize 32 patches into Al ----
  {
    int b = mtile >> 5;                   // batch image (32 m-tiles each)
    int pbase = (mtile & 31) * 32;        // 32 consecutive positions (one y row)
    #pragma unroll 2
    for (int i = 0; i < 20; ++i) {
      int d = i * 256 + tid;                            // [0,5120) dwords
      unsigned int m_l = ((unsigned)d * 52429u) >> 23;  // d/160
      int kw = d - (int)m_l * 160;
      int p = pbase + (int)m_l;
      int y = p >> 5, x = p & 31;
      unsigned int pack = 0;
      #pragma unroll
      for (int q = 0; q < 4; ++q) {
        int k = kw * 4 + q;
        int c = k >> 7, j = k & 127;
        int csize = (c == 4) ? 112 : 116;
        unsigned int bv = 0;
        if (j < csize) {
          unsigned int f  = c * 116 + j;          // f = ic*9 + dy*3 + dx
          unsigned int ic = (f * 7282u) >> 16;    // f/9
          unsigned int r9 = f - ic * 9u;
          unsigned int dy = (r9 * 11u) >> 5;      // r9/3
          unsigned int dx = r9 - dy * 3u;
          int iy = y + (int)dy - 1, ix = x + (int)dx - 1;
          if (iy >= 0 && iy < 32 && ix >= 0 && ix < 32) {
            float xv = in[((b * 64 + (int)ic) * 32 + iy) * 32 + ix];
            xv = fminf(fmaxf(xv, -8.0f), 7.9375f);      // fixed-point clip
            bv = (unsigned int)((int)rintf(xv * 16.0f) & 255);  // 2's-compl byte
          }
        }
        pack |= bv << (8 * q);
      }
      ((unsigned int*)Al)[(int)m_l * 164 + kw] = pack;
    }
  }

  // ---- phase 3: weight |max| partials (weights are L2-resident) ----
  {
    const float4* w4 = (const float4*)w;
    float a = 0.0f;
    #pragma unroll 4
    for (int i = 0; i < 36; ++i) {
      float4 v = w4[i * 256 + tid];
      a = fmaxf(a, fmaxf(fmaxf(fabsf(v.x), fabsf(v.y)),
                         fmaxf(fabsf(v.z), fabsf(v.w))));
    }
    #pragma unroll
    for (int off = 32; off > 0; off >>= 1)
      a = fmaxf(a, __shfl_down(a, off, 64));
    if ((tid & 63) == 0) s_part[tid >> 6] = a;
  }
  __syncthreads();

  float norm = fmaxf(fmaxf(s_part[0], s_part[1]), fmaxf(s_part[2], s_part[3]));
  if (!(norm > 0.0f)) norm = 1.0f;
  float sc = 255.0f / norm;

  // ---- phase 4: quantize 32 o x 576 f weights into Bl (float4 groups) ----
  #pragma unroll 2
  for (int i = 0; i < 18; ++i) {
    int idx = i * 256 + tid;                                  // [0,4608)
    unsigned int o_l = (((unsigned)idx >> 4) * 7282u) >> 16;  // idx/144
    int g = idx - (int)o_l * 144;
    int c, jg;
    if (g < 116) { c = (g * 565) >> 14; jg = (g - c * 29) * 4; }  // c=g/29
    else         { c = 4;               jg = (g - 116) * 4; }
    int f = c * 116 + jg;                                     // f%4==0 -> float4 ok
    float4 wv = *(const float4*)(w + (ohalf * 32 + (int)o_l) * 576 + f);
    float vv[4] = {wv.x, wv.y, wv.z, wv.w};
    unsigned int pd = 0, nd = 0;
    #pragma unroll
    for (int q = 0; q < 4; ++q) {
      unsigned int pb = (unsigned int)(int)rintf(fmaxf(vv[q], 0.0f) * sc);
      unsigned int nb = (unsigned int)(int)rintf(fmaxf(-vv[q], 0.0f) * sc);
      pd |= pb << (8 * q);
      nd |= nb << (8 * q);
    }
    int dwo = c * 32 + (jg >> 2);
    ((unsigned int*)Bl)[((int)o_l) * 164 + dwo]       = pd;   // pos
    ((unsigned int*)Bl)[(32 + (int)o_l) * 164 + dwo]  = nd;   // neg
  }
  __syncthreads();

  // ---- phase 5: MFMA main loop (weights = A-operand, patches = B-operand) ----
  int lane = tid & 63, wave = tid >> 6;
  int msub = wave >> 1, osub = wave & 1;   // 2x2 wave subtiles of 16m x 16o
  int r16 = lane & 15, kgrp = lane >> 4;

  const unsigned char* ap = Al + (msub * 16 + r16) * BROW + kgrp * 16;       // patch frag
  const unsigned char* bp = Bl + (osub * 16 + r16) * BROW + kgrp * 16;       // pos weights
  const unsigned char* bn = Bl + (32 + osub * 16 + r16) * BROW + kgrp * 16;  // neg weights

  v4i outacc = {0, 0, 0, 0};

  #pragma unroll
  for (int c = 0; c < 5; ++c) {
    v4u a0 = *(const v4u*)(ap + c * 128);        // patch bytes, kblk 0
    v4u a1 = *(const v4u*)(ap + c * 128 + 64);   // kblk 1
    v4u p0 = *(const v4u*)(bp + c * 128);
    v4u p1 = *(const v4u*)(bp + c * 128 + 64);
    v4u n0 = *(const v4u*)(bn + c * 128);
    v4u n1 = *(const v4u*)(bn + c * 128 + 64);

    v4i btp0[4], btp1[4], btn0[4], btn1[4];      // slice frags, reused over s
    #pragma unroll
    for (int t = 0; t < 4; ++t) {
      btp0[t] = bits2(p0, t); btp1[t] = bits2(p1, t);
      btn0[t] = bits2(n0, t); btn1[t] = bits2(n1, t);
    }

    #pragma unroll
    for (int s = 0; s < 4; ++s) {
      v4i as0 = bits2(a0, s), as1 = bits2(a1, s);
      #pragma unroll
      for (int t = 0; t < 4; ++t) {
        v4i z = {0, 0, 0, 0};
        // D[o][m]: weights as A-operand, patches as B-operand
        v4i pacc = __builtin_amdgcn_mfma_i32_16x16x64_i8(btp0[t], as0, z, 0, 0, 0);
        pacc     = __builtin_amdgcn_mfma_i32_16x16x64_i8(btp1[t], as1, pacc, 0, 0, 0);
        v4i nacc = __builtin_amdgcn_mfma_i32_16x16x64_i8(btn0[t], as0, z, 0, 0, 0);
        nacc     = __builtin_amdgcn_mfma_i32_16x16x64_i8(btn1[t], as1, nacc, 0, 0, 0);
        int sh = 2 * (s + t);
        #pragma unroll
        for (int r = 0; r < 4; ++r) {
          // ADC: nonneg int sums; clip(round(x),0,31) == min(x,31)
          int d = (pacc[r] < 31 ? pacc[r] : 31) - (nacc[r] < 31 ? nacc[r] : 31);
          outacc[r] += d << sh;   // |outacc| <= 31*85*85*5 ~ 1.12e6, exact
        }
      }
    }
  }

  // ---- epilogue: D layout col(m)=lane&15, row(o)=kgrp*4+r -> p-contiguous ----
  float fsc = norm / 255.0f;
  int m = mtile * 32 + msub * 16 + r16;
  int b = m >> 10, p = m & 1023;
  int oc = ohalf * 32 + osub * 16 + kgrp * 4;
  #pragma unroll
  for (int r = 0; r < 4; ++r)
    out[(b * 64 + oc + r) * 1024 + p] = (float)outacc[r] * fsc;
}

extern "C" void kernel_launch(void* const* d_in, const int* in_sizes, int n_in,
                              void* d_out, int out_size, void* d_ws, size_t ws_size,
                              hipStream_t stream) {
  const float* inp = (const float*)d_in[0];   // (4,64,32,32) f32
  const float* wgt = (const float*)d_in[1];   // (64,64,3,3)  f32
  float* out = (float*)d_out;                 // 262144 + 1 f32
  (void)d_ws; (void)ws_size;
  k_fused<<<256, 256, 0, stream>>>(inp, wgt, out);
}